// Round 1
// baseline (1589.276 us; speedup 1.0000x reference)
//
#include <hip/hip_runtime.h>
#include <math.h>

// ---------------------------------------------------------------------------
// EdgeGAT: 3x GAT (segment-softmax attention, self-loops) + BN folded into
// next GEMM + edge-MLP folded into final per-edge kernel.
// Structure: device-built dst-CSR (no atomics in the heavy aggregation pass),
// one wave per destination node, coalesced 1KB h-row gathers.
// ---------------------------------------------------------------------------

#define FIN 128
#define HID 64

// ---------------- CSR build ----------------

__global__ void count_kernel(const int* __restrict__ ei, int* __restrict__ deg,
                             int E, int Etot) {
    int e = blockIdx.x * 256 + threadIdx.x;
    if (e >= Etot) return;
    int d = (e < E) ? ei[E + e] : (e - E);
    atomicAdd(&deg[d], 1);
}

// single-block exclusive scan: deg (in) -> row_ptr, and deg overwritten with
// cursor (= row_ptr value) for the scatter pass.
__global__ void scan_kernel(int* __restrict__ deg_cursor, int* __restrict__ row_ptr,
                            int N) {
    __shared__ int wsum[16];
    int t = threadIdx.x;
    int lane = t & 63;
    int wid = t >> 6;
    int base = 0;
    for (int start = 0; start < N; start += 1024) {
        int i = start + t;
        int v = (i < N) ? deg_cursor[i] : 0;
        int x = v;
        #pragma unroll
        for (int o = 1; o < 64; o <<= 1) {
            int y = __shfl_up(x, o);
            if (lane >= o) x += y;
        }
        if (lane == 63) wsum[wid] = x;
        __syncthreads();
        int woff = 0, tot = 0;
        #pragma unroll
        for (int w = 0; w < 16; ++w) {
            int s = wsum[w];
            if (w < wid) woff += s;
            tot += s;
        }
        if (i < N) {
            int excl = base + woff + x - v;
            row_ptr[i] = excl;
            deg_cursor[i] = excl;
        }
        base += tot;
        __syncthreads();
    }
    if (t == 0) row_ptr[N] = base;
}

__global__ void scatter_kernel(const int* __restrict__ ei, int* __restrict__ cursor,
                               int* __restrict__ col, int E, int Etot) {
    int e = blockIdx.x * 256 + threadIdx.x;
    if (e >= Etot) return;
    int s, d;
    if (e < E) { s = ei[e]; d = ei[E + e]; }
    else       { s = e - E; d = e - E; }
    int pos = atomicAdd(&cursor[d], 1);
    col[pos] = s;
}

// ---------------- GEMM: Y[N,M] = (X*scale+shift)[N,K] @ W[K,M] ----------------
// 64x64 tile, 256 threads, 4x4 microtile, K-chunk 32.

__global__ __launch_bounds__(256) void gemm_kernel(
    const float* __restrict__ X, const float* __restrict__ W,
    float* __restrict__ Y, int Nrows, int K, int M,
    const float* __restrict__ scale, const float* __restrict__ shift) {
    __shared__ __align__(16) float As[32][68];
    __shared__ __align__(16) float Bs[32][68];
    const int t = threadIdx.x;
    const int row0 = blockIdx.x * 64;
    const int c0 = blockIdx.y * 64;
    const int tm = t >> 4, tn = t & 15;
    const int ar = t >> 3, akq = t & 7;
    const int bk = t >> 4, bq = t & 15;
    float acc[4][4] = {};
    for (int k0 = 0; k0 < K; k0 += 32) {
        #pragma unroll
        for (int hh = 0; hh < 2; ++hh) {
            int r = ar + 32 * hh;
            int grow = row0 + r;
            int gk = k0 + akq * 4;
            float4 xv = make_float4(0.f, 0.f, 0.f, 0.f);
            if (grow < Nrows) xv = *(const float4*)(X + (size_t)grow * K + gk);
            if (scale) {
                float4 sc = *(const float4*)(scale + gk);
                float4 sh = *(const float4*)(shift + gk);
                xv.x = fmaf(xv.x, sc.x, sh.x);
                xv.y = fmaf(xv.y, sc.y, sh.y);
                xv.z = fmaf(xv.z, sc.z, sh.z);
                xv.w = fmaf(xv.w, sc.w, sh.w);
            }
            As[akq * 4 + 0][r] = xv.x;
            As[akq * 4 + 1][r] = xv.y;
            As[akq * 4 + 2][r] = xv.z;
            As[akq * 4 + 3][r] = xv.w;
            int kk = bk + 16 * hh;
            *(float4*)&Bs[kk][bq * 4] =
                *(const float4*)(W + (size_t)(k0 + kk) * M + c0 + bq * 4);
        }
        __syncthreads();
        #pragma unroll
        for (int k = 0; k < 32; ++k) {
            float4 a4 = *(const float4*)&As[k][tm * 4];
            float4 b4 = *(const float4*)&Bs[k][tn * 4];
            float av[4] = {a4.x, a4.y, a4.z, a4.w};
            float bv[4] = {b4.x, b4.y, b4.z, b4.w};
            #pragma unroll
            for (int i = 0; i < 4; ++i)
                #pragma unroll
                for (int j = 0; j < 4; ++j)
                    acc[i][j] = fmaf(av[i], bv[j], acc[i][j]);
        }
        __syncthreads();
    }
    #pragma unroll
    for (int i = 0; i < 4; ++i) {
        int grow = row0 + tm * 4 + i;
        if (grow < Nrows) {
            float4 o = make_float4(acc[i][0], acc[i][1], acc[i][2], acc[i][3]);
            *(float4*)(Y + (size_t)grow * M + c0 + tn * 4) = o;
        }
    }
}

// ---------------- attention coefficients ls/ld per node ----------------

template <int H>
__global__ __launch_bounds__(256) void attn_coef_kernel(
    const float* __restrict__ h, const float* __restrict__ as_,
    const float* __restrict__ ad_, float* __restrict__ ls,
    float* __restrict__ ld, int N) {
    constexpr int C = 64 * H;
    int lane = threadIdx.x & 63;
    int n = blockIdx.x * 4 + (threadIdx.x >> 6);
    if (n >= N) return;
    float su[H], sd[H];
    #pragma unroll
    for (int j = 0; j < H; ++j) {
        float hv = h[(size_t)n * C + j * 64 + lane];
        su[j] = hv * as_[j * 64 + lane];
        sd[j] = hv * ad_[j * 64 + lane];
    }
    #pragma unroll
    for (int j = 0; j < H; ++j) {
        #pragma unroll
        for (int o = 32; o; o >>= 1) {
            su[j] += __shfl_xor(su[j], o);
            sd[j] += __shfl_xor(sd[j], o);
        }
        if (lane == j) {
            ls[(size_t)n * H + j] = su[j];
            ld[(size_t)n * H + j] = sd[j];
        }
    }
}

// ---------------- aggregation: one wave per destination node ----------------
// MODE 0: out = elu(sum alpha*h + b)  (written for BN stats later)
// MODE 1: (H=1) u[n] = (out+b).fcW[0:64], v[n] = (out+b).fcW[64:128]

template <int H, int MODE>
__global__ __launch_bounds__(256) void agg_kernel(
    const float* __restrict__ h, const float* __restrict__ ls,
    const float* __restrict__ ld, const int* __restrict__ row_ptr,
    const int* __restrict__ col, const float* __restrict__ bias,
    float* __restrict__ out, const float* __restrict__ fcW,
    float* __restrict__ up, float* __restrict__ vp, int N) {
    constexpr int C = 64 * H;
    int lane = threadIdx.x & 63;
    int n = blockIdx.x * 4 + (threadIdx.x >> 6);
    if (n >= N) return;
    int head = (lane * H) >> 6;  // H=4: lane/16 ; H=1: 0
    int c0 = lane * H;
    float ldn = ld[(size_t)n * H + head];
    int beg = row_ptr[n], end = row_ptr[n + 1];
    // pass 1: segment max of leaky_relu logits
    float m = -1e30f;
    for (int e = beg; e < end; ++e) {
        int s = col[e];
        float lg = ls[(size_t)s * H + head] + ldn;
        lg = (lg >= 0.f) ? lg : 0.2f * lg;
        m = fmaxf(m, lg);
    }
    if (m < -1e29f) m = 0.f;  // empty-segment guard (ref: where(isfinite,m,0))
    // pass 2: p=exp(lg-m); s+=p; acc+=p*h[src]
    float ssum = 0.f;
    float acc[H];
    #pragma unroll
    for (int i = 0; i < H; ++i) acc[i] = 0.f;
    for (int e = beg; e < end; ++e) {
        int s = col[e];
        float lg = ls[(size_t)s * H + head] + ldn;
        lg = (lg >= 0.f) ? lg : 0.2f * lg;
        float p = __expf(lg - m);
        ssum += p;
        const float* hr = h + (size_t)s * C + c0;
        if (H == 4) {
            float4 hv = *(const float4*)hr;
            acc[0] = fmaf(p, hv.x, acc[0]);
            acc[1] = fmaf(p, hv.y, acc[1]);
            acc[2] = fmaf(p, hv.z, acc[2]);
            acc[3] = fmaf(p, hv.w, acc[3]);
        } else {
            acc[0] = fmaf(p, hr[0], acc[0]);
        }
    }
    float inv = 1.f / (ssum + 1e-16f);
    if (MODE == 0) {
        if (H == 4) {
            float4 bv = *(const float4*)(bias + c0);
            float4 o;
            o.x = fmaf(acc[0], inv, bv.x);
            o.y = fmaf(acc[1], inv, bv.y);
            o.z = fmaf(acc[2], inv, bv.z);
            o.w = fmaf(acc[3], inv, bv.w);
            o.x = (o.x > 0.f) ? o.x : expm1f(o.x);
            o.y = (o.y > 0.f) ? o.y : expm1f(o.y);
            o.z = (o.z > 0.f) ? o.z : expm1f(o.z);
            o.w = (o.w > 0.f) ? o.w : expm1f(o.w);
            *(float4*)(out + (size_t)n * C + c0) = o;
        } else {
            float o = fmaf(acc[0], inv, bias[c0]);
            o = (o > 0.f) ? o : expm1f(o);
            out[(size_t)n * C + c0] = o;
        }
    } else {
        // H == 1: final layer -> per-node dot products with fc weights
        float val = fmaf(acc[0], inv, bias[c0]);
        float pu = val * fcW[c0];
        float pv = val * fcW[64 + c0];
        #pragma unroll
        for (int o = 32; o; o >>= 1) {
            pu += __shfl_xor(pu, o);
            pv += __shfl_xor(pv, o);
        }
        if (lane == 0) {
            up[n] = pu;
            vp[n] = pv;
        }
    }
}

// ---------------- BN stats + finalize (fold into next GEMM load) ----------------

__global__ __launch_bounds__(256) void bn_stats_kernel(const float* __restrict__ y,
                                                       float* __restrict__ sums,
                                                       int N) {
    int c = threadIdx.x;  // 256 channels
    int r0 = blockIdx.x * 128;
    int rend = min(r0 + 128, N);
    float s = 0.f, s2 = 0.f;
    for (int r = r0; r < rend; ++r) {
        float v = y[(size_t)r * 256 + c];
        s += v;
        s2 += v * v;
    }
    atomicAdd(&sums[c], s);
    atomicAdd(&sums[256 + c], s2);
}

__global__ void bn_finalize_kernel(const float* __restrict__ sums,
                                   const float* __restrict__ g,
                                   const float* __restrict__ b,
                                   float* __restrict__ scale,
                                   float* __restrict__ shift, int N) {
    int c = threadIdx.x;
    float invN = 1.f / (float)N;
    float mu = sums[c] * invN;
    float var = sums[256 + c] * invN - mu * mu;
    float sc = g[c] * rsqrtf(var + 1e-5f);
    scale[c] = sc;
    shift[c] = b[c] - mu * sc;
}

// ---------------- final edge kernel prep + output ----------------

__global__ void prep_kernel(const float* __restrict__ mlpW2,
                            const float* __restrict__ mlpb2,
                            const float* __restrict__ fcW,
                            const float* __restrict__ fcb,
                            float* __restrict__ w2f, float* __restrict__ c2) {
    int j = threadIdx.x;  // 64
    float s = 0.f;
    for (int k = 0; k < 64; ++k) s += mlpW2[j * 64 + k] * fcW[128 + k];
    w2f[j] = s;
    if (j == 0) {
        float c = fcb[0];
        for (int k = 0; k < 64; ++k) c += mlpb2[k] * fcW[128 + k];
        c2[0] = c;
    }
}

__global__ __launch_bounds__(256) void edge_out_kernel(
    const int* __restrict__ ei, const float* __restrict__ ea,
    const float* __restrict__ W1, const float* __restrict__ b1,
    const float* __restrict__ w2f, const float* __restrict__ c2p,
    const float* __restrict__ u, const float* __restrict__ v,
    float* __restrict__ out, int E) {
    __shared__ __align__(16) float W1T[64][16];  // [j][i] = W1[i][j]
    __shared__ float w2fl[64];
    __shared__ float b1l[64];
    int t = threadIdx.x;
    for (int p = t; p < 1024; p += 256) {
        int i = p >> 6, j = p & 63;
        W1T[j][i] = W1[i * 64 + j];
    }
    if (t < 64) {
        w2fl[t] = w2f[t];
        b1l[t] = b1[t];
    }
    __syncthreads();
    int e = blockIdx.x * 256 + t;
    if (e >= E) return;
    int s0 = ei[e];
    int d0 = ei[E + e];
    const float4* ear = (const float4*)(ea + (size_t)e * 16);
    float4 q0 = ear[0], q1 = ear[1], q2 = ear[2], q3 = ear[3];
    float eav[16] = {q0.x, q0.y, q0.z, q0.w, q1.x, q1.y, q1.z, q1.w,
                     q2.x, q2.y, q2.z, q2.w, q3.x, q3.y, q3.z, q3.w};
    float acc = 0.f;
    #pragma unroll 8
    for (int j = 0; j < 64; ++j) {
        const float4* wr = (const float4*)&W1T[j][0];
        float4 w0 = wr[0], w1 = wr[1], w2 = wr[2], w3 = wr[3];
        float s = b1l[j];
        s = fmaf(eav[0], w0.x, s);  s = fmaf(eav[1], w0.y, s);
        s = fmaf(eav[2], w0.z, s);  s = fmaf(eav[3], w0.w, s);
        s = fmaf(eav[4], w1.x, s);  s = fmaf(eav[5], w1.y, s);
        s = fmaf(eav[6], w1.z, s);  s = fmaf(eav[7], w1.w, s);
        s = fmaf(eav[8], w2.x, s);  s = fmaf(eav[9], w2.y, s);
        s = fmaf(eav[10], w2.z, s); s = fmaf(eav[11], w2.w, s);
        s = fmaf(eav[12], w3.x, s); s = fmaf(eav[13], w3.y, s);
        s = fmaf(eav[14], w3.z, s); s = fmaf(eav[15], w3.w, s);
        s = fmaxf(s, 0.f);
        acc = fmaf(s, w2fl[j], acc);
    }
    out[e] = u[s0] + v[d0] + acc + c2p[0];
}

// ---------------- orchestration ----------------

extern "C" void kernel_launch(void* const* d_in, const int* in_sizes, int n_in,
                              void* d_out, int out_size, void* d_ws, size_t ws_size,
                              hipStream_t stream) {
    const float* x     = (const float*)d_in[0];
    const int*   ei    = (const int*)d_in[1];
    const float* ea    = (const float*)d_in[2];
    const float* W1    = (const float*)d_in[3];
    const float* a1s   = (const float*)d_in[4];
    const float* a1d   = (const float*)d_in[5];
    const float* b1    = (const float*)d_in[6];
    const float* W2    = (const float*)d_in[7];
    const float* a2s   = (const float*)d_in[8];
    const float* a2d   = (const float*)d_in[9];
    const float* b2    = (const float*)d_in[10];
    const float* W3    = (const float*)d_in[11];
    const float* a3s   = (const float*)d_in[12];
    const float* a3d   = (const float*)d_in[13];
    const float* b3    = (const float*)d_in[14];
    const float* bn1g  = (const float*)d_in[15];
    const float* bn1b  = (const float*)d_in[16];
    const float* bn2g  = (const float*)d_in[17];
    const float* bn2b  = (const float*)d_in[18];
    const float* mlpW1 = (const float*)d_in[19];
    const float* mlpb1 = (const float*)d_in[20];
    const float* mlpW2 = (const float*)d_in[21];
    const float* mlpb2 = (const float*)d_in[22];
    const float* fcW   = (const float*)d_in[23];
    const float* fcb   = (const float*)d_in[24];
    float* out = (float*)d_out;

    const int N = in_sizes[0] / FIN;     // 50000
    const int E = in_sizes[1] / 2;       // 1600000
    const int Etot = E + N;

    // workspace layout (all chunks 16-element aligned)
    float* ws = (float*)d_ws;
    size_t off = 0;
    float* hA = ws + off;        off += (size_t)N * 256;
    float* hB = ws + off;        off += (size_t)N * 256;
    float* lsb = ws + off;       off += (size_t)N * 4;
    float* ldb = ws + off;       off += (size_t)N * 4;
    int* row_ptr = (int*)(ws + off); off += (size_t)(N + 16);
    int* cursor  = (int*)(ws + off); off += (size_t)N;   // also deg
    int* colb    = (int*)(ws + off); off += (size_t)(Etot + 15) / 16 * 16;
    float* bnsum   = ws + off;   off += 512;
    float* bnscale = ws + off;   off += 256;
    float* bnshift = ws + off;   off += 256;
    float* ub  = ws + off;       off += (size_t)N;
    float* vb  = ws + off;       off += (size_t)N;
    float* w2f = ws + off;       off += 64;
    float* c2  = ws + off;       off += 16;
    (void)ws_size; (void)n_in; (void)out_size;

    const int nbE = (Etot + 255) / 256;
    const int nb4 = (N + 3) / 4;

    // CSR build (dst-sorted)
    hipMemsetAsync(cursor, 0, (size_t)N * sizeof(int), stream);
    count_kernel<<<nbE, 256, 0, stream>>>(ei, cursor, E, Etot);
    scan_kernel<<<1, 1024, 0, stream>>>(cursor, row_ptr, N);
    scatter_kernel<<<nbE, 256, 0, stream>>>(ei, cursor, colb, E, Etot);

    dim3 gemm_grid((N + 63) / 64, 4);
    dim3 gemm_grid3((N + 63) / 64, 1);

    // ---- layer 1 ----
    gemm_kernel<<<gemm_grid, 256, 0, stream>>>(x, W1, hA, N, 128, 256, nullptr, nullptr);
    attn_coef_kernel<4><<<nb4, 256, 0, stream>>>(hA, a1s, a1d, lsb, ldb, N);
    agg_kernel<4, 0><<<nb4, 256, 0, stream>>>(hA, lsb, ldb, row_ptr, colb, b1, hB,
                                              nullptr, nullptr, nullptr, N);
    hipMemsetAsync(bnsum, 0, 512 * sizeof(float), stream);
    bn_stats_kernel<<<(N + 127) / 128, 256, 0, stream>>>(hB, bnsum, N);
    bn_finalize_kernel<<<1, 256, 0, stream>>>(bnsum, bn1g, bn1b, bnscale, bnshift, N);

    // ---- layer 2 ----
    gemm_kernel<<<gemm_grid, 256, 0, stream>>>(hB, W2, hA, N, 256, 256, bnscale, bnshift);
    attn_coef_kernel<4><<<nb4, 256, 0, stream>>>(hA, a2s, a2d, lsb, ldb, N);
    agg_kernel<4, 0><<<nb4, 256, 0, stream>>>(hA, lsb, ldb, row_ptr, colb, b2, hB,
                                              nullptr, nullptr, nullptr, N);
    hipMemsetAsync(bnsum, 0, 512 * sizeof(float), stream);
    bn_stats_kernel<<<(N + 127) / 128, 256, 0, stream>>>(hB, bnsum, N);
    bn_finalize_kernel<<<1, 256, 0, stream>>>(bnsum, bn2g, bn2b, bnscale, bnshift, N);

    // ---- layer 3 ----
    gemm_kernel<<<gemm_grid3, 256, 0, stream>>>(hB, W3, hA, N, 256, 64, bnscale, bnshift);
    attn_coef_kernel<1><<<nb4, 256, 0, stream>>>(hA, a3s, a3d, lsb, ldb, N);
    agg_kernel<1, 1><<<nb4, 256, 0, stream>>>(hA, lsb, ldb, row_ptr, colb, b3, nullptr,
                                              fcW, ub, vb, N);

    // ---- edge output ----
    prep_kernel<<<1, 64, 0, stream>>>(mlpW2, mlpb2, fcW, fcb, w2f, c2);
    edge_out_kernel<<<(E + 255) / 256, 256, 0, stream>>>(ei, ea, mlpW1, mlpb1, w2f, c2,
                                                         ub, vb, out, E);
}

// Round 2
// 1180.113 us; speedup vs baseline: 1.3467x; 1.3467x over previous
//
#include <hip/hip_runtime.h>
#include <math.h>

// ---------------------------------------------------------------------------
// EdgeGAT: 3x GAT (segment-softmax attention, self-loops) + BN folded into
// next GEMM + edge-MLP folded into final per-edge kernel.
// R2: h stored bf16 for the gather path (half bytes); aggregation restructured
// to lane-parallel max sweep + shfl-broadcast accumulate sweep (no dependent
// scalar-gather chains). Accumulation stays f32.
// ---------------------------------------------------------------------------

#define FIN 128
#define HID 64

__device__ __forceinline__ unsigned f2bfbits(float f) {
    unsigned u = __float_as_uint(f);
    return (u + 0x7fffu + ((u >> 16) & 1u)) >> 16;  // RNE
}
__device__ __forceinline__ float bf_lo(unsigned w) { return __uint_as_float(w << 16); }
__device__ __forceinline__ float bf_hi(unsigned w) { return __uint_as_float(w & 0xffff0000u); }
__device__ __forceinline__ float bf1(unsigned short s) { return __uint_as_float(((unsigned)s) << 16); }

// ---------------- CSR build ----------------

__global__ void count_kernel(const int* __restrict__ ei, int* __restrict__ deg,
                             int E, int Etot) {
    int e = blockIdx.x * 256 + threadIdx.x;
    if (e >= Etot) return;
    int d = (e < E) ? ei[E + e] : (e - E);
    atomicAdd(&deg[d], 1);
}

__global__ void scan_kernel(int* __restrict__ deg_cursor, int* __restrict__ row_ptr,
                            int N) {
    __shared__ int wsum[16];
    int t = threadIdx.x;
    int lane = t & 63;
    int wid = t >> 6;
    int base = 0;
    for (int start = 0; start < N; start += 1024) {
        int i = start + t;
        int v = (i < N) ? deg_cursor[i] : 0;
        int x = v;
        #pragma unroll
        for (int o = 1; o < 64; o <<= 1) {
            int y = __shfl_up(x, o);
            if (lane >= o) x += y;
        }
        if (lane == 63) wsum[wid] = x;
        __syncthreads();
        int woff = 0, tot = 0;
        #pragma unroll
        for (int w = 0; w < 16; ++w) {
            int s = wsum[w];
            if (w < wid) woff += s;
            tot += s;
        }
        if (i < N) {
            int excl = base + woff + x - v;
            row_ptr[i] = excl;
            deg_cursor[i] = excl;
        }
        base += tot;
        __syncthreads();
    }
    if (t == 0) row_ptr[N] = base;
}

__global__ void scatter_kernel(const int* __restrict__ ei, int* __restrict__ cursor,
                               int* __restrict__ col, int E, int Etot) {
    int e = blockIdx.x * 256 + threadIdx.x;
    if (e >= Etot) return;
    int s, d;
    if (e < E) { s = ei[e]; d = ei[E + e]; }
    else       { s = e - E; d = e - E; }
    int pos = atomicAdd(&cursor[d], 1);
    col[pos] = s;
}

// ---------------- GEMM: Yb[N,M](bf16) = (X*scale+shift)[N,K] @ W[K,M] --------
// 64x64 tile, 256 threads, 4x4 microtile, K-chunk 32. Output bf16.

__global__ __launch_bounds__(256) void gemm_kernel(
    const float* __restrict__ X, const float* __restrict__ W,
    unsigned short* __restrict__ Yb, int Nrows, int K, int M,
    const float* __restrict__ scale, const float* __restrict__ shift) {
    __shared__ __align__(16) float As[32][68];
    __shared__ __align__(16) float Bs[32][68];
    const int t = threadIdx.x;
    const int row0 = blockIdx.x * 64;
    const int c0 = blockIdx.y * 64;
    const int tm = t >> 4, tn = t & 15;
    const int ar = t >> 3, akq = t & 7;
    const int bk = t >> 4, bq = t & 15;
    float acc[4][4] = {};
    for (int k0 = 0; k0 < K; k0 += 32) {
        #pragma unroll
        for (int hh = 0; hh < 2; ++hh) {
            int r = ar + 32 * hh;
            int grow = row0 + r;
            int gk = k0 + akq * 4;
            float4 xv = make_float4(0.f, 0.f, 0.f, 0.f);
            if (grow < Nrows) xv = *(const float4*)(X + (size_t)grow * K + gk);
            if (scale) {
                float4 sc = *(const float4*)(scale + gk);
                float4 sh = *(const float4*)(shift + gk);
                xv.x = fmaf(xv.x, sc.x, sh.x);
                xv.y = fmaf(xv.y, sc.y, sh.y);
                xv.z = fmaf(xv.z, sc.z, sh.z);
                xv.w = fmaf(xv.w, sc.w, sh.w);
            }
            As[akq * 4 + 0][r] = xv.x;
            As[akq * 4 + 1][r] = xv.y;
            As[akq * 4 + 2][r] = xv.z;
            As[akq * 4 + 3][r] = xv.w;
            int kk = bk + 16 * hh;
            *(float4*)&Bs[kk][bq * 4] =
                *(const float4*)(W + (size_t)(k0 + kk) * M + c0 + bq * 4);
        }
        __syncthreads();
        #pragma unroll
        for (int k = 0; k < 32; ++k) {
            float4 a4 = *(const float4*)&As[k][tm * 4];
            float4 b4 = *(const float4*)&Bs[k][tn * 4];
            float av[4] = {a4.x, a4.y, a4.z, a4.w};
            float bv[4] = {b4.x, b4.y, b4.z, b4.w};
            #pragma unroll
            for (int i = 0; i < 4; ++i)
                #pragma unroll
                for (int j = 0; j < 4; ++j)
                    acc[i][j] = fmaf(av[i], bv[j], acc[i][j]);
        }
        __syncthreads();
    }
    #pragma unroll
    for (int i = 0; i < 4; ++i) {
        int grow = row0 + tm * 4 + i;
        if (grow < Nrows) {
            uint2 pk;
            pk.x = f2bfbits(acc[i][0]) | (f2bfbits(acc[i][1]) << 16);
            pk.y = f2bfbits(acc[i][2]) | (f2bfbits(acc[i][3]) << 16);
            *(uint2*)(Yb + (size_t)grow * M + c0 + tn * 4) = pk;
        }
    }
}

// ---------------- attention coefficients ls/ld per node (bf16 h) -------------

template <int H>
__global__ __launch_bounds__(256) void attn_coef_kernel(
    const unsigned short* __restrict__ hb, const float* __restrict__ as_,
    const float* __restrict__ ad_, float* __restrict__ ls,
    float* __restrict__ ld, int N) {
    int lane = threadIdx.x & 63;
    int n = blockIdx.x * 4 + (threadIdx.x >> 6);
    if (n >= N) return;
    if (H == 4) {
        uint2 w = *(const uint2*)(hb + (size_t)n * 256 + lane * 4);
        float h0 = bf_lo(w.x), h1 = bf_hi(w.x), h2 = bf_lo(w.y), h3 = bf_hi(w.y);
        int cg = lane * 4;
        float4 av = *(const float4*)(as_ + cg);
        float4 dv = *(const float4*)(ad_ + cg);
        float su = h0 * av.x + h1 * av.y + h2 * av.z + h3 * av.w;
        float sd = h0 * dv.x + h1 * dv.y + h2 * dv.z + h3 * dv.w;
        #pragma unroll
        for (int o = 1; o < 16; o <<= 1) {
            su += __shfl_xor(su, o);
            sd += __shfl_xor(sd, o);
        }
        if ((lane & 15) == 0) {
            int hd = lane >> 4;
            ls[(size_t)n * 4 + hd] = su;
            ld[(size_t)n * 4 + hd] = sd;
        }
    } else {
        float hv = bf1(hb[(size_t)n * 64 + lane]);
        float su = hv * as_[lane];
        float sd = hv * ad_[lane];
        #pragma unroll
        for (int o = 32; o; o >>= 1) {
            su += __shfl_xor(su, o);
            sd += __shfl_xor(sd, o);
        }
        if (lane == 0) {
            ls[n] = su;
            ld[n] = sd;
        }
    }
}

// ---------------- aggregation: one wave per destination node ----------------
// Sweep A: lane-parallel segment max (64 edges at a time).
// Sweep B: shfl-broadcast src id; each lane recomputes p for its own head
// (replicated within 16-lane head groups -> denominator needs no reduce).
// MODE 0: out = elu(sum alpha*h + b)   MODE 1 (H=1): u,v = (out+b).fcW halves

template <int H, int MODE>
__global__ __launch_bounds__(256) void agg_kernel(
    const unsigned short* __restrict__ hb, const float* __restrict__ ls,
    const float* __restrict__ ld, const int* __restrict__ row_ptr,
    const int* __restrict__ col, const float* __restrict__ bias,
    float* __restrict__ out, const float* __restrict__ fcW,
    float* __restrict__ up, float* __restrict__ vp, int N) {
    constexpr int C = 64 * H;
    int lane = threadIdx.x & 63;
    int n = blockIdx.x * 4 + (threadIdx.x >> 6);
    if (n >= N) return;
    int beg = row_ptr[n], end = row_ptr[n + 1];
    const int hd = (H == 4) ? (lane >> 4) : 0;

    float mx[H];
    #pragma unroll
    for (int h = 0; h < H; ++h) mx[h] = -1e30f;
    float ldn_h;
    if (H == 4) {
        float4 ldn = *(const float4*)(ld + (size_t)n * 4);
        for (int base = beg; base < end; base += 64) {
            int el = base + lane;
            if (el < end) {
                int s = col[el];
                float4 l4 = *(const float4*)(ls + (size_t)s * 4);
                float lg;
                lg = l4.x + ldn.x; lg = lg >= 0.f ? lg : 0.2f * lg; mx[0] = fmaxf(mx[0], lg);
                lg = l4.y + ldn.y; lg = lg >= 0.f ? lg : 0.2f * lg; mx[1] = fmaxf(mx[1], lg);
                lg = l4.z + ldn.z; lg = lg >= 0.f ? lg : 0.2f * lg; mx[2] = fmaxf(mx[2], lg);
                lg = l4.w + ldn.w; lg = lg >= 0.f ? lg : 0.2f * lg; mx[3] = fmaxf(mx[3], lg);
            }
        }
        ldn_h = (hd == 0) ? ldn.x : (hd == 1) ? ldn.y : (hd == 2) ? ldn.z : ldn.w;
    } else {
        float ldn = ld[n];
        for (int base = beg; base < end; base += 64) {
            int el = base + lane;
            if (el < end) {
                int s = col[el];
                float lg = ls[s] + ldn;
                lg = lg >= 0.f ? lg : 0.2f * lg;
                mx[0] = fmaxf(mx[0], lg);
            }
        }
        ldn_h = ldn;
    }
    #pragma unroll
    for (int h = 0; h < H; ++h) {
        #pragma unroll
        for (int o = 32; o; o >>= 1) mx[h] = fmaxf(mx[h], __shfl_xor(mx[h], o));
        if (mx[h] < -1e29f) mx[h] = 0.f;  // empty-segment guard
    }
    float m_h = (H == 4)
                    ? ((hd == 0) ? mx[0] : (hd == 1) ? mx[1] : (hd == 2) ? mx[2] : mx[3])
                    : mx[0];

    const int c0 = (H == 4) ? lane * 4 : lane;
    float psum = 0.f;
    float acc0 = 0.f, acc1 = 0.f, acc2 = 0.f, acc3 = 0.f;
    for (int base = beg; base < end; base += 64) {
        int el = base + lane;
        int s_r = (el < end) ? col[el] : 0;
        int cnt = min(64, end - base);
        for (int j = 0; j < cnt; ++j) {
            int sj = __shfl(s_r, j);
            float lsv = ls[(size_t)sj * H + hd];
            float lg = lsv + ldn_h;
            lg = lg >= 0.f ? lg : 0.2f * lg;
            float pv = __expf(lg - m_h);
            psum += pv;
            if (H == 4) {
                uint2 w = *(const uint2*)(hb + (size_t)sj * 256 + c0);
                acc0 = fmaf(pv, bf_lo(w.x), acc0);
                acc1 = fmaf(pv, bf_hi(w.x), acc1);
                acc2 = fmaf(pv, bf_lo(w.y), acc2);
                acc3 = fmaf(pv, bf_hi(w.y), acc3);
            } else {
                acc0 = fmaf(pv, bf1(hb[(size_t)sj * 64 + lane]), acc0);
            }
        }
    }
    float inv = 1.f / (psum + 1e-16f);
    if (MODE == 0) {
        float4 bv = *(const float4*)(bias + c0);
        float4 o;
        o.x = fmaf(acc0, inv, bv.x);
        o.y = fmaf(acc1, inv, bv.y);
        o.z = fmaf(acc2, inv, bv.z);
        o.w = fmaf(acc3, inv, bv.w);
        o.x = (o.x > 0.f) ? o.x : expm1f(o.x);
        o.y = (o.y > 0.f) ? o.y : expm1f(o.y);
        o.z = (o.z > 0.f) ? o.z : expm1f(o.z);
        o.w = (o.w > 0.f) ? o.w : expm1f(o.w);
        *(float4*)(out + (size_t)n * C + c0) = o;
    } else {
        float val = fmaf(acc0, inv, bias[lane]);
        float pu = val * fcW[lane];
        float pv2 = val * fcW[64 + lane];
        #pragma unroll
        for (int o = 32; o; o >>= 1) {
            pu += __shfl_xor(pu, o);
            pv2 += __shfl_xor(pv2, o);
        }
        if (lane == 0) {
            up[n] = pu;
            vp[n] = pv2;
        }
    }
}

// ---------------- BN stats + finalize (fold into next GEMM load) ------------

__global__ __launch_bounds__(256) void bn_stats_kernel(const float* __restrict__ y,
                                                       float* __restrict__ sums,
                                                       int N) {
    int c = threadIdx.x;
    int r0 = blockIdx.x * 128;
    int rend = min(r0 + 128, N);
    float s = 0.f, s2 = 0.f;
    for (int r = r0; r < rend; ++r) {
        float v = y[(size_t)r * 256 + c];
        s += v;
        s2 += v * v;
    }
    atomicAdd(&sums[c], s);
    atomicAdd(&sums[256 + c], s2);
}

__global__ void bn_finalize_kernel(const float* __restrict__ sums,
                                   const float* __restrict__ g,
                                   const float* __restrict__ b,
                                   float* __restrict__ scale,
                                   float* __restrict__ shift, int N) {
    int c = threadIdx.x;
    float invN = 1.f / (float)N;
    float mu = sums[c] * invN;
    float var = sums[256 + c] * invN - mu * mu;
    float sc = g[c] * rsqrtf(var + 1e-5f);
    scale[c] = sc;
    shift[c] = b[c] - mu * sc;
}

// ---------------- final edge kernel prep + output ----------------

__global__ void prep_kernel(const float* __restrict__ mlpW2,
                            const float* __restrict__ mlpb2,
                            const float* __restrict__ fcW,
                            const float* __restrict__ fcb,
                            float* __restrict__ w2f, float* __restrict__ c2) {
    int j = threadIdx.x;  // 64
    float s = 0.f;
    for (int k = 0; k < 64; ++k) s += mlpW2[j * 64 + k] * fcW[128 + k];
    w2f[j] = s;
    if (j == 0) {
        float c = fcb[0];
        for (int k = 0; k < 64; ++k) c += mlpb2[k] * fcW[128 + k];
        c2[0] = c;
    }
}

__global__ __launch_bounds__(256) void edge_out_kernel(
    const int* __restrict__ ei, const float* __restrict__ ea,
    const float* __restrict__ W1, const float* __restrict__ b1,
    const float* __restrict__ w2f, const float* __restrict__ c2p,
    const float* __restrict__ u, const float* __restrict__ v,
    float* __restrict__ out, int E) {
    __shared__ __align__(16) float W1T[64][16];
    __shared__ float w2fl[64];
    __shared__ float b1l[64];
    int t = threadIdx.x;
    for (int p = t; p < 1024; p += 256) {
        int i = p >> 6, j = p & 63;
        W1T[j][i] = W1[i * 64 + j];
    }
    if (t < 64) {
        w2fl[t] = w2f[t];
        b1l[t] = b1[t];
    }
    __syncthreads();
    int e = blockIdx.x * 256 + t;
    if (e >= E) return;
    int s0 = ei[e];
    int d0 = ei[E + e];
    const float4* ear = (const float4*)(ea + (size_t)e * 16);
    float4 q0 = ear[0], q1 = ear[1], q2 = ear[2], q3 = ear[3];
    float eav[16] = {q0.x, q0.y, q0.z, q0.w, q1.x, q1.y, q1.z, q1.w,
                     q2.x, q2.y, q2.z, q2.w, q3.x, q3.y, q3.z, q3.w};
    float acc = 0.f;
    #pragma unroll 8
    for (int j = 0; j < 64; ++j) {
        const float4* wr = (const float4*)&W1T[j][0];
        float4 w0 = wr[0], w1 = wr[1], w2 = wr[2], w3 = wr[3];
        float s = b1l[j];
        s = fmaf(eav[0], w0.x, s);  s = fmaf(eav[1], w0.y, s);
        s = fmaf(eav[2], w0.z, s);  s = fmaf(eav[3], w0.w, s);
        s = fmaf(eav[4], w1.x, s);  s = fmaf(eav[5], w1.y, s);
        s = fmaf(eav[6], w1.z, s);  s = fmaf(eav[7], w1.w, s);
        s = fmaf(eav[8], w2.x, s);  s = fmaf(eav[9], w2.y, s);
        s = fmaf(eav[10], w2.z, s); s = fmaf(eav[11], w2.w, s);
        s = fmaf(eav[12], w3.x, s); s = fmaf(eav[13], w3.y, s);
        s = fmaf(eav[14], w3.z, s); s = fmaf(eav[15], w3.w, s);
        s = fmaxf(s, 0.f);
        acc = fmaf(s, w2fl[j], acc);
    }
    out[e] = u[s0] + v[d0] + acc + c2p[0];
}

// ---------------- orchestration ----------------

extern "C" void kernel_launch(void* const* d_in, const int* in_sizes, int n_in,
                              void* d_out, int out_size, void* d_ws, size_t ws_size,
                              hipStream_t stream) {
    const float* x     = (const float*)d_in[0];
    const int*   ei    = (const int*)d_in[1];
    const float* ea    = (const float*)d_in[2];
    const float* W1    = (const float*)d_in[3];
    const float* a1s   = (const float*)d_in[4];
    const float* a1d   = (const float*)d_in[5];
    const float* b1    = (const float*)d_in[6];
    const float* W2    = (const float*)d_in[7];
    const float* a2s   = (const float*)d_in[8];
    const float* a2d   = (const float*)d_in[9];
    const float* b2    = (const float*)d_in[10];
    const float* W3    = (const float*)d_in[11];
    const float* a3s   = (const float*)d_in[12];
    const float* a3d   = (const float*)d_in[13];
    const float* b3    = (const float*)d_in[14];
    const float* bn1g  = (const float*)d_in[15];
    const float* bn1b  = (const float*)d_in[16];
    const float* bn2g  = (const float*)d_in[17];
    const float* bn2b  = (const float*)d_in[18];
    const float* mlpW1 = (const float*)d_in[19];
    const float* mlpb1 = (const float*)d_in[20];
    const float* mlpW2 = (const float*)d_in[21];
    const float* mlpb2 = (const float*)d_in[22];
    const float* fcW   = (const float*)d_in[23];
    const float* fcb   = (const float*)d_in[24];
    float* out = (float*)d_out;

    const int N = in_sizes[0] / FIN;     // 50000
    const int E = in_sizes[1] / 2;       // 1600000
    const int Etot = E + N;

    // workspace layout (byte cursor, 16B aligned chunks)
    char* wsb = (char*)d_ws;
    size_t off = 0;
    auto alloc = [&](size_t bytes) {
        void* p = wsb + off;
        off += (bytes + 15) & ~(size_t)15;
        return p;
    };
    unsigned short* hAb = (unsigned short*)alloc((size_t)N * 256 * 2);  // bf16 h (layers 1,2,3 gemm out)
    float* hB  = (float*)alloc((size_t)N * 256 * 4);                    // f32 agg out
    unsigned short* h3b = (unsigned short*)alloc((size_t)N * 64 * 2);   // bf16 layer-3 gemm out
    float* lsb = (float*)alloc((size_t)N * 4 * 4);
    float* ldb = (float*)alloc((size_t)N * 4 * 4);
    int* row_ptr = (int*)alloc((size_t)(N + 1) * 4);
    int* cursor  = (int*)alloc((size_t)N * 4);
    int* colb    = (int*)alloc((size_t)Etot * 4);
    float* bnsum   = (float*)alloc(512 * 4);
    float* bnscale = (float*)alloc(256 * 4);
    float* bnshift = (float*)alloc(256 * 4);
    float* ub  = (float*)alloc((size_t)N * 4);
    float* vb  = (float*)alloc((size_t)N * 4);
    float* w2f = (float*)alloc(64 * 4);
    float* c2  = (float*)alloc(16 * 4);
    (void)ws_size; (void)n_in; (void)out_size;

    const int nbE = (Etot + 255) / 256;
    const int nb4 = (N + 3) / 4;

    // CSR build (dst-sorted)
    hipMemsetAsync(cursor, 0, (size_t)N * sizeof(int), stream);
    count_kernel<<<nbE, 256, 0, stream>>>(ei, cursor, E, Etot);
    scan_kernel<<<1, 1024, 0, stream>>>(cursor, row_ptr, N);
    scatter_kernel<<<nbE, 256, 0, stream>>>(ei, cursor, colb, E, Etot);

    dim3 gemm_grid((N + 63) / 64, 4);
    dim3 gemm_grid3((N + 63) / 64, 1);

    // ---- layer 1 ----
    gemm_kernel<<<gemm_grid, 256, 0, stream>>>(x, W1, hAb, N, 128, 256, nullptr, nullptr);
    attn_coef_kernel<4><<<nb4, 256, 0, stream>>>(hAb, a1s, a1d, lsb, ldb, N);
    agg_kernel<4, 0><<<nb4, 256, 0, stream>>>(hAb, lsb, ldb, row_ptr, colb, b1, hB,
                                              nullptr, nullptr, nullptr, N);
    hipMemsetAsync(bnsum, 0, 512 * sizeof(float), stream);
    bn_stats_kernel<<<(N + 127) / 128, 256, 0, stream>>>(hB, bnsum, N);
    bn_finalize_kernel<<<1, 256, 0, stream>>>(bnsum, bn1g, bn1b, bnscale, bnshift, N);

    // ---- layer 2 ----
    gemm_kernel<<<gemm_grid, 256, 0, stream>>>(hB, W2, hAb, N, 256, 256, bnscale, bnshift);
    attn_coef_kernel<4><<<nb4, 256, 0, stream>>>(hAb, a2s, a2d, lsb, ldb, N);
    agg_kernel<4, 0><<<nb4, 256, 0, stream>>>(hAb, lsb, ldb, row_ptr, colb, b2, hB,
                                              nullptr, nullptr, nullptr, N);
    hipMemsetAsync(bnsum, 0, 512 * sizeof(float), stream);
    bn_stats_kernel<<<(N + 127) / 128, 256, 0, stream>>>(hB, bnsum, N);
    bn_finalize_kernel<<<1, 256, 0, stream>>>(bnsum, bn2g, bn2b, bnscale, bnshift, N);

    // ---- layer 3 ----
    gemm_kernel<<<gemm_grid3, 256, 0, stream>>>(hB, W3, h3b, N, 256, 64, bnscale, bnshift);
    attn_coef_kernel<1><<<nb4, 256, 0, stream>>>(h3b, a3s, a3d, lsb, ldb, N);
    agg_kernel<1, 1><<<nb4, 256, 0, stream>>>(h3b, lsb, ldb, row_ptr, colb, b3, nullptr,
                                              fcW, ub, vb, N);

    // ---- edge output ----
    prep_kernel<<<1, 64, 0, stream>>>(mlpW2, mlpb2, fcW, fcb, w2f, c2);
    edge_out_kernel<<<(E + 255) / 256, 256, 0, stream>>>(ei, ea, mlpW1, mlpb1, w2f, c2,
                                                         ub, vb, out, E);
}

// Round 3
// 1053.220 us; speedup vs baseline: 1.5090x; 1.1205x over previous
//
#include <hip/hip_runtime.h>
#include <math.h>

// ---------------------------------------------------------------------------
// EdgeGAT R3:
//  - Binned CSR build: bin by dst>>8 (LDS histograms, contiguous bin scatter,
//    per-bin LDS-local CSR) -> replaces global-atomic count/scan/scatter.
//  - agg: max sweep removed. m = max(0, ld[n]+LSMAX[h]) with LSMAX = global
//    per-head max of ls (computed in attn_coef via block reduce + atomicMax).
//    Softmax shift cancels in alpha; eps-inflation e^(m-max)*1e-16 negligible.
//  - h kept bf16 for gather path; accumulation f32.
// ---------------------------------------------------------------------------

#define FIN 128
#define HID 64
#define BIN_SHIFT 8   // 256 nodes per bin; requires N <= 65536

__device__ __forceinline__ unsigned f2bfbits(float f) {
    unsigned u = __float_as_uint(f);
    return (u + 0x7fffu + ((u >> 16) & 1u)) >> 16;  // RNE
}
__device__ __forceinline__ float bf_lo(unsigned w) { return __uint_as_float(w << 16); }
__device__ __forceinline__ float bf_hi(unsigned w) { return __uint_as_float(w & 0xffff0000u); }
__device__ __forceinline__ float bf1(unsigned short s) { return __uint_as_float(((unsigned)s) << 16); }

// monotone float<->uint encoding for atomicMax on floats
__device__ __forceinline__ unsigned fenc(float f) {
    unsigned b = __float_as_uint(f);
    return (b & 0x80000000u) ? ~b : (b | 0x80000000u);
}
__device__ __forceinline__ float fdec(unsigned k) {
    unsigned b = (k & 0x80000000u) ? (k ^ 0x80000000u) : ~k;
    return __uint_as_float(b);
}

// ---------------- binned CSR build ----------------
// P0: global bin counts (LDS pre-aggregated)
__global__ __launch_bounds__(256) void bincount_kernel(const int* __restrict__ ei,
                                                       int* __restrict__ bincnt,
                                                       int E, int Etot) {
    __shared__ int h[256];
    int t = threadIdx.x;
    h[t] = 0;
    __syncthreads();
    int base = blockIdx.x * 4096;
    #pragma unroll
    for (int i = 0; i < 16; ++i) {
        int e = base + i * 256 + t;
        if (e < Etot) {
            int d = (e < E) ? ei[E + e] : (e - E);
            atomicAdd(&h[d >> BIN_SHIFT], 1);
        }
    }
    __syncthreads();
    if (h[t]) atomicAdd(&bincnt[t], h[t]);
}

// scan of bin counts -> binptr[NB+1], bincur[NB]
__global__ void scanbins_kernel(const int* __restrict__ bincnt, int* __restrict__ binptr,
                                int* __restrict__ bincur, int NB, int Etot) {
    __shared__ int buf[256];
    int t = threadIdx.x;  // 256
    int v = (t < NB) ? bincnt[t] : 0;
    buf[t] = v;
    __syncthreads();
    for (int o = 1; o < 256; o <<= 1) {
        int y = (t >= o) ? buf[t - o] : 0;
        __syncthreads();
        buf[t] += y;
        __syncthreads();
    }
    int excl = buf[t] - v;
    if (t < NB) {
        binptr[t] = excl;
        bincur[t] = excl;
    }
    if (t == 0) binptr[NB] = Etot;
}

// P1: scatter (s,d) pairs into contiguous bins, per-block LDS allocation
__global__ __launch_bounds__(256) void binscatter_kernel(const int* __restrict__ ei,
                                                         int* __restrict__ bincur,
                                                         int2* __restrict__ binned,
                                                         int E, int Etot) {
    __shared__ int h[256];
    __shared__ int gb[256];
    int t = threadIdx.x;
    h[t] = 0;
    __syncthreads();
    int base = blockIdx.x * 4096;
    #pragma unroll
    for (int i = 0; i < 16; ++i) {
        int e = base + i * 256 + t;
        if (e < Etot) {
            int d = (e < E) ? ei[E + e] : (e - E);
            atomicAdd(&h[d >> BIN_SHIFT], 1);
        }
    }
    __syncthreads();
    int cnt = h[t];
    if (cnt) gb[t] = atomicAdd(&bincur[t], cnt);
    __syncthreads();
    h[t] = 0;
    __syncthreads();
    #pragma unroll
    for (int i = 0; i < 16; ++i) {
        int e = base + i * 256 + t;
        if (e < Etot) {
            int s, d;
            if (e < E) { s = ei[e]; d = ei[E + e]; }
            else       { s = e - E; d = e - E; }
            int b = d >> BIN_SHIFT;
            int pos = gb[b] + atomicAdd(&h[b], 1);
            binned[pos] = make_int2(s, d);
        }
    }
}

// per-bin CSR: LDS histogram + scan -> row_ptr chunk; LDS cursors -> col
__global__ __launch_bounds__(256) void bincsr_kernel(const int2* __restrict__ binned,
                                                     const int* __restrict__ binptr,
                                                     int* __restrict__ row_ptr,
                                                     int* __restrict__ col,
                                                     int N, int Etot) {
    __shared__ int h[256];
    __shared__ int cur[256];
    __shared__ int wsum[4];
    int b = blockIdx.x;
    int t = threadIdx.x;
    int lo = b << BIN_SHIFT;
    h[t] = 0;
    __syncthreads();
    int ebeg = binptr[b], eend = binptr[b + 1];
    for (int i = ebeg + t; i < eend; i += 256) atomicAdd(&h[binned[i].y - lo], 1);
    __syncthreads();
    int v = h[t];
    int lane = t & 63, w = t >> 6;
    int x = v;
    #pragma unroll
    for (int o = 1; o < 64; o <<= 1) {
        int y = __shfl_up(x, o);
        if (lane >= o) x += y;
    }
    if (lane == 63) wsum[w] = x;
    __syncthreads();
    int off = 0;
    #pragma unroll
    for (int i = 0; i < 4; ++i) off += (i < w) ? wsum[i] : 0;
    int excl = ebeg + off + x - v;
    int node = lo + t;
    if (node < N) row_ptr[node] = excl;
    cur[t] = excl;
    if (b == 0 && t == 0) row_ptr[N] = Etot;
    __syncthreads();
    for (int i = ebeg + t; i < eend; i += 256) {
        int2 sd = binned[i];
        int pos = atomicAdd(&cur[sd.y - lo], 1);
        col[pos] = sd.x;
    }
}

// ---------------- GEMM: Yb[N,M](bf16) = (X*scale+shift)[N,K] @ W[K,M] --------

__global__ __launch_bounds__(256) void gemm_kernel(
    const float* __restrict__ X, const float* __restrict__ W,
    unsigned short* __restrict__ Yb, int Nrows, int K, int M,
    const float* __restrict__ scale, const float* __restrict__ shift) {
    __shared__ __align__(16) float As[32][68];
    __shared__ __align__(16) float Bs[32][68];
    const int t = threadIdx.x;
    const int row0 = blockIdx.x * 64;
    const int c0 = blockIdx.y * 64;
    const int tm = t >> 4, tn = t & 15;
    const int ar = t >> 3, akq = t & 7;
    const int bk = t >> 4, bq = t & 15;
    float acc[4][4] = {};
    for (int k0 = 0; k0 < K; k0 += 32) {
        #pragma unroll
        for (int hh = 0; hh < 2; ++hh) {
            int r = ar + 32 * hh;
            int grow = row0 + r;
            int gk = k0 + akq * 4;
            float4 xv = make_float4(0.f, 0.f, 0.f, 0.f);
            if (grow < Nrows) xv = *(const float4*)(X + (size_t)grow * K + gk);
            if (scale) {
                float4 sc = *(const float4*)(scale + gk);
                float4 sh = *(const float4*)(shift + gk);
                xv.x = fmaf(xv.x, sc.x, sh.x);
                xv.y = fmaf(xv.y, sc.y, sh.y);
                xv.z = fmaf(xv.z, sc.z, sh.z);
                xv.w = fmaf(xv.w, sc.w, sh.w);
            }
            As[akq * 4 + 0][r] = xv.x;
            As[akq * 4 + 1][r] = xv.y;
            As[akq * 4 + 2][r] = xv.z;
            As[akq * 4 + 3][r] = xv.w;
            int kk = bk + 16 * hh;
            *(float4*)&Bs[kk][bq * 4] =
                *(const float4*)(W + (size_t)(k0 + kk) * M + c0 + bq * 4);
        }
        __syncthreads();
        #pragma unroll
        for (int k = 0; k < 32; ++k) {
            float4 a4 = *(const float4*)&As[k][tm * 4];
            float4 b4 = *(const float4*)&Bs[k][tn * 4];
            float av[4] = {a4.x, a4.y, a4.z, a4.w};
            float bv[4] = {b4.x, b4.y, b4.z, b4.w};
            #pragma unroll
            for (int i = 0; i < 4; ++i)
                #pragma unroll
                for (int j = 0; j < 4; ++j)
                    acc[i][j] = fmaf(av[i], bv[j], acc[i][j]);
        }
        __syncthreads();
    }
    #pragma unroll
    for (int i = 0; i < 4; ++i) {
        int grow = row0 + tm * 4 + i;
        if (grow < Nrows) {
            uint2 pk;
            pk.x = f2bfbits(acc[i][0]) | (f2bfbits(acc[i][1]) << 16);
            pk.y = f2bfbits(acc[i][2]) | (f2bfbits(acc[i][3]) << 16);
            *(uint2*)(Yb + (size_t)grow * M + c0 + tn * 4) = pk;
        }
    }
}

// ---------------- attention coefficients + global ls-max ----------------

template <int H>
__global__ __launch_bounds__(256) void attn_coef_kernel(
    const unsigned short* __restrict__ hb, const float* __restrict__ as_,
    const float* __restrict__ ad_, float* __restrict__ ls,
    float* __restrict__ ld, unsigned* __restrict__ lsmax_g, int N, int ngroups) {
    __shared__ unsigned lmax_lds[4];
    int t = threadIdx.x;
    if (t < 4) lmax_lds[t] = 0;
    __syncthreads();
    int lane = t & 63;
    float lmax = -3.0e38f;
    for (int g = blockIdx.x; g < ngroups; g += gridDim.x) {
        int n = g * 4 + (t >> 6);
        if (n >= N) continue;
        if (H == 4) {
            uint2 w = *(const uint2*)(hb + (size_t)n * 256 + lane * 4);
            float h0 = bf_lo(w.x), h1 = bf_hi(w.x), h2 = bf_lo(w.y), h3 = bf_hi(w.y);
            int cg = lane * 4;
            float4 av = *(const float4*)(as_ + cg);
            float4 dv = *(const float4*)(ad_ + cg);
            float su = h0 * av.x + h1 * av.y + h2 * av.z + h3 * av.w;
            float sd = h0 * dv.x + h1 * dv.y + h2 * dv.z + h3 * dv.w;
            #pragma unroll
            for (int o = 1; o < 16; o <<= 1) {
                su += __shfl_xor(su, o);
                sd += __shfl_xor(sd, o);
            }
            if ((lane & 15) == 0) {
                int hd = lane >> 4;
                ls[(size_t)n * 4 + hd] = su;
                ld[(size_t)n * 4 + hd] = sd;
            }
            lmax = fmaxf(lmax, su);
        } else {
            float hv = bf1(hb[(size_t)n * 64 + lane]);
            float su = hv * as_[lane];
            float sd = hv * ad_[lane];
            #pragma unroll
            for (int o = 32; o; o >>= 1) {
                su += __shfl_xor(su, o);
                sd += __shfl_xor(sd, o);
            }
            if (lane == 0) {
                ls[n] = su;
                ld[n] = sd;
            }
            lmax = fmaxf(lmax, su);
        }
    }
    unsigned key = fenc(lmax);
    if (H == 4) {
        if ((lane & 15) == 0) atomicMax(&lmax_lds[lane >> 4], key);
    } else {
        if (lane == 0) atomicMax(&lmax_lds[0], key);
    }
    __syncthreads();
    if (t < H) atomicMax(&lsmax_g[t], lmax_lds[t]);
}

// ---------------- aggregation: one wave per dst node, single sweep ----------
// m = max(0, ld[n]+LSMAX[h]) >= true segment max; shift cancels in alpha.

template <int H, int MODE>
__global__ __launch_bounds__(256) void agg_kernel(
    const unsigned short* __restrict__ hb, const float* __restrict__ ls,
    const float* __restrict__ ld, const int* __restrict__ row_ptr,
    const int* __restrict__ col, const float* __restrict__ bias,
    float* __restrict__ out, const float* __restrict__ fcW,
    float* __restrict__ up, float* __restrict__ vp,
    const unsigned* __restrict__ lsmax_g, int N) {
    constexpr int C = 64 * H;
    int lane = threadIdx.x & 63;
    int n = blockIdx.x * 4 + (threadIdx.x >> 6);
    if (n >= N) return;
    int beg = row_ptr[n], end = row_ptr[n + 1];
    const int hd = (H == 4) ? (lane >> 4) : 0;

    float ldn_h, m_h;
    if (H == 4) {
        float4 ldn = *(const float4*)(ld + (size_t)n * 4);
        ldn_h = (hd == 0) ? ldn.x : (hd == 1) ? ldn.y : (hd == 2) ? ldn.z : ldn.w;
        m_h = fmaxf(0.f, ldn_h + fdec(lsmax_g[hd]));
    } else {
        ldn_h = ld[n];
        m_h = fmaxf(0.f, ldn_h + fdec(lsmax_g[0]));
    }

    const int c0 = (H == 4) ? lane * 4 : lane;
    float psum = 0.f;
    float acc0 = 0.f, acc1 = 0.f, acc2 = 0.f, acc3 = 0.f;
    for (int base = beg; base < end; base += 64) {
        int el = base + lane;
        int s_r = (el < end) ? col[el] : 0;
        int cnt = min(64, end - base);
        for (int j = 0; j < cnt; ++j) {
            int sj = __shfl(s_r, j);
            float lsv = ls[(size_t)sj * H + hd];
            float lg = lsv + ldn_h;
            lg = lg >= 0.f ? lg : 0.2f * lg;
            float pv = __expf(lg - m_h);
            psum += pv;
            if (H == 4) {
                uint2 w = *(const uint2*)(hb + (size_t)sj * 256 + c0);
                acc0 = fmaf(pv, bf_lo(w.x), acc0);
                acc1 = fmaf(pv, bf_hi(w.x), acc1);
                acc2 = fmaf(pv, bf_lo(w.y), acc2);
                acc3 = fmaf(pv, bf_hi(w.y), acc3);
            } else {
                acc0 = fmaf(pv, bf1(hb[(size_t)sj * 64 + lane]), acc0);
            }
        }
    }
    float inv = 1.f / (psum + 1e-16f);
    if (MODE == 0) {
        float4 bv = *(const float4*)(bias + c0);
        float4 o;
        o.x = fmaf(acc0, inv, bv.x);
        o.y = fmaf(acc1, inv, bv.y);
        o.z = fmaf(acc2, inv, bv.z);
        o.w = fmaf(acc3, inv, bv.w);
        o.x = (o.x > 0.f) ? o.x : expm1f(o.x);
        o.y = (o.y > 0.f) ? o.y : expm1f(o.y);
        o.z = (o.z > 0.f) ? o.z : expm1f(o.z);
        o.w = (o.w > 0.f) ? o.w : expm1f(o.w);
        *(float4*)(out + (size_t)n * C + c0) = o;
    } else {
        float val = fmaf(acc0, inv, bias[lane]);
        float pu = val * fcW[lane];
        float pv2 = val * fcW[64 + lane];
        #pragma unroll
        for (int o = 32; o; o >>= 1) {
            pu += __shfl_xor(pu, o);
            pv2 += __shfl_xor(pv2, o);
        }
        if (lane == 0) {
            up[n] = pu;
            vp[n] = pv2;
        }
    }
}

// ---------------- BN stats + finalize ----------------

__global__ __launch_bounds__(256) void bn_stats_kernel(const float* __restrict__ y,
                                                       float* __restrict__ sums,
                                                       int N) {
    int c = threadIdx.x;
    int r0 = blockIdx.x * 128;
    int rend = min(r0 + 128, N);
    float s = 0.f, s2 = 0.f;
    for (int r = r0; r < rend; ++r) {
        float v = y[(size_t)r * 256 + c];
        s += v;
        s2 += v * v;
    }
    atomicAdd(&sums[c], s);
    atomicAdd(&sums[256 + c], s2);
}

__global__ void bn_finalize_kernel(const float* __restrict__ sums,
                                   const float* __restrict__ g,
                                   const float* __restrict__ b,
                                   float* __restrict__ scale,
                                   float* __restrict__ shift, int N) {
    int c = threadIdx.x;
    float invN = 1.f / (float)N;
    float mu = sums[c] * invN;
    float var = sums[256 + c] * invN - mu * mu;
    float sc = g[c] * rsqrtf(var + 1e-5f);
    scale[c] = sc;
    shift[c] = b[c] - mu * sc;
}

// ---------------- final edge kernel prep + output ----------------

__global__ void prep_kernel(const float* __restrict__ mlpW2,
                            const float* __restrict__ mlpb2,
                            const float* __restrict__ fcW,
                            const float* __restrict__ fcb,
                            float* __restrict__ w2f, float* __restrict__ c2) {
    int j = threadIdx.x;  // 64
    float s = 0.f;
    for (int k = 0; k < 64; ++k) s += mlpW2[j * 64 + k] * fcW[128 + k];
    w2f[j] = s;
    if (j == 0) {
        float c = fcb[0];
        for (int k = 0; k < 64; ++k) c += mlpb2[k] * fcW[128 + k];
        c2[0] = c;
    }
}

__global__ __launch_bounds__(256) void edge_out_kernel(
    const int* __restrict__ ei, const float* __restrict__ ea,
    const float* __restrict__ W1, const float* __restrict__ b1,
    const float* __restrict__ w2f, const float* __restrict__ c2p,
    const float* __restrict__ u, const float* __restrict__ v,
    float* __restrict__ out, int E) {
    __shared__ __align__(16) float W1T[64][16];
    __shared__ float w2fl[64];
    __shared__ float b1l[64];
    int t = threadIdx.x;
    for (int p = t; p < 1024; p += 256) {
        int i = p >> 6, j = p & 63;
        W1T[j][i] = W1[i * 64 + j];
    }
    if (t < 64) {
        w2fl[t] = w2f[t];
        b1l[t] = b1[t];
    }
    __syncthreads();
    int e = blockIdx.x * 256 + t;
    if (e >= E) return;
    int s0 = ei[e];
    int d0 = ei[E + e];
    const float4* ear = (const float4*)(ea + (size_t)e * 16);
    float4 q0 = ear[0], q1 = ear[1], q2 = ear[2], q3 = ear[3];
    float eav[16] = {q0.x, q0.y, q0.z, q0.w, q1.x, q1.y, q1.z, q1.w,
                     q2.x, q2.y, q2.z, q2.w, q3.x, q3.y, q3.z, q3.w};
    float acc = 0.f;
    #pragma unroll 8
    for (int j = 0; j < 64; ++j) {
        const float4* wr = (const float4*)&W1T[j][0];
        float4 w0 = wr[0], w1 = wr[1], w2 = wr[2], w3 = wr[3];
        float s = b1l[j];
        s = fmaf(eav[0], w0.x, s);  s = fmaf(eav[1], w0.y, s);
        s = fmaf(eav[2], w0.z, s);  s = fmaf(eav[3], w0.w, s);
        s = fmaf(eav[4], w1.x, s);  s = fmaf(eav[5], w1.y, s);
        s = fmaf(eav[6], w1.z, s);  s = fmaf(eav[7], w1.w, s);
        s = fmaf(eav[8], w2.x, s);  s = fmaf(eav[9], w2.y, s);
        s = fmaf(eav[10], w2.z, s); s = fmaf(eav[11], w2.w, s);
        s = fmaf(eav[12], w3.x, s); s = fmaf(eav[13], w3.y, s);
        s = fmaf(eav[14], w3.z, s); s = fmaf(eav[15], w3.w, s);
        s = fmaxf(s, 0.f);
        acc = fmaf(s, w2fl[j], acc);
    }
    out[e] = u[s0] + v[d0] + acc + c2p[0];
}

// ---------------- orchestration ----------------

extern "C" void kernel_launch(void* const* d_in, const int* in_sizes, int n_in,
                              void* d_out, int out_size, void* d_ws, size_t ws_size,
                              hipStream_t stream) {
    const float* x     = (const float*)d_in[0];
    const int*   ei    = (const int*)d_in[1];
    const float* ea    = (const float*)d_in[2];
    const float* W1    = (const float*)d_in[3];
    const float* a1s   = (const float*)d_in[4];
    const float* a1d   = (const float*)d_in[5];
    const float* b1    = (const float*)d_in[6];
    const float* W2    = (const float*)d_in[7];
    const float* a2s   = (const float*)d_in[8];
    const float* a2d   = (const float*)d_in[9];
    const float* b2    = (const float*)d_in[10];
    const float* W3    = (const float*)d_in[11];
    const float* a3s   = (const float*)d_in[12];
    const float* a3d   = (const float*)d_in[13];
    const float* b3    = (const float*)d_in[14];
    const float* bn1g  = (const float*)d_in[15];
    const float* bn1b  = (const float*)d_in[16];
    const float* bn2g  = (const float*)d_in[17];
    const float* bn2b  = (const float*)d_in[18];
    const float* mlpW1 = (const float*)d_in[19];
    const float* mlpb1 = (const float*)d_in[20];
    const float* mlpW2 = (const float*)d_in[21];
    const float* mlpb2 = (const float*)d_in[22];
    const float* fcW   = (const float*)d_in[23];
    const float* fcb   = (const float*)d_in[24];
    float* out = (float*)d_out;

    const int N = in_sizes[0] / FIN;     // 50000
    const int E = in_sizes[1] / 2;       // 1600000
    const int Etot = E + N;
    const int NB = (N + 255) >> BIN_SHIFT;  // 196

    // workspace layout
    char* wsb = (char*)d_ws;
    size_t off = 0;
    auto alloc = [&](size_t bytes) {
        void* p = wsb + off;
        off += (bytes + 15) & ~(size_t)15;
        return p;
    };
    unsigned short* hAb = (unsigned short*)alloc((size_t)N * 256 * 2);
    float* hB  = (float*)alloc((size_t)N * 256 * 4);
    unsigned short* h3b = (unsigned short*)alloc((size_t)N * 64 * 2);
    float* lsb = (float*)alloc((size_t)N * 4 * 4);
    float* ldb = (float*)alloc((size_t)N * 4 * 4);
    int* row_ptr = (int*)alloc((size_t)(N + 1) * 4);
    int* colb    = (int*)alloc((size_t)Etot * 4);
    int2* binned = (int2*)alloc((size_t)Etot * 8);
    // contiguous zero-init region: bincnt[256] + lsmax[3][4]
    int* bincnt  = (int*)alloc(256 * 4 + 12 * 4);
    unsigned* lsmax1 = (unsigned*)(bincnt + 256);
    unsigned* lsmax2 = lsmax1 + 4;
    unsigned* lsmax3 = lsmax1 + 8;
    int* binptr  = (int*)alloc((size_t)(NB + 1) * 4);
    int* bincur  = (int*)alloc((size_t)NB * 4);
    float* bnsum   = (float*)alloc(512 * 4);
    float* bnscale = (float*)alloc(256 * 4);
    float* bnshift = (float*)alloc(256 * 4);
    float* ub  = (float*)alloc((size_t)N * 4);
    float* vb  = (float*)alloc((size_t)N * 4);
    float* w2f = (float*)alloc(64 * 4);
    float* c2  = (float*)alloc(16 * 4);
    (void)ws_size; (void)n_in; (void)out_size;

    const int nb4 = (N + 3) / 4;
    const int nch = (Etot + 4095) / 4096;

    // ---- binned CSR build ----
    hipMemsetAsync(bincnt, 0, (256 + 12) * sizeof(int), stream);
    bincount_kernel<<<nch, 256, 0, stream>>>(ei, bincnt, E, Etot);
    scanbins_kernel<<<1, 256, 0, stream>>>(bincnt, binptr, bincur, NB, Etot);
    binscatter_kernel<<<nch, 256, 0, stream>>>(ei, bincur, binned, E, Etot);
    bincsr_kernel<<<NB, 256, 0, stream>>>(binned, binptr, row_ptr, colb, N, Etot);

    dim3 gemm_grid((N + 63) / 64, 4);
    dim3 gemm_grid3((N + 63) / 64, 1);

    // ---- layer 1 ----
    gemm_kernel<<<gemm_grid, 256, 0, stream>>>(x, W1, hAb, N, 128, 256, nullptr, nullptr);
    attn_coef_kernel<4><<<2048, 256, 0, stream>>>(hAb, a1s, a1d, lsb, ldb, lsmax1, N, nb4);
    agg_kernel<4, 0><<<nb4, 256, 0, stream>>>(hAb, lsb, ldb, row_ptr, colb, b1, hB,
                                              nullptr, nullptr, nullptr, lsmax1, N);
    hipMemsetAsync(bnsum, 0, 512 * sizeof(float), stream);
    bn_stats_kernel<<<(N + 127) / 128, 256, 0, stream>>>(hB, bnsum, N);
    bn_finalize_kernel<<<1, 256, 0, stream>>>(bnsum, bn1g, bn1b, bnscale, bnshift, N);

    // ---- layer 2 ----
    gemm_kernel<<<gemm_grid, 256, 0, stream>>>(hB, W2, hAb, N, 256, 256, bnscale, bnshift);
    attn_coef_kernel<4><<<2048, 256, 0, stream>>>(hAb, a2s, a2d, lsb, ldb, lsmax2, N, nb4);
    agg_kernel<4, 0><<<nb4, 256, 0, stream>>>(hAb, lsb, ldb, row_ptr, colb, b2, hB,
                                              nullptr, nullptr, nullptr, lsmax2, N);
    hipMemsetAsync(bnsum, 0, 512 * sizeof(float), stream);
    bn_stats_kernel<<<(N + 127) / 128, 256, 0, stream>>>(hB, bnsum, N);
    bn_finalize_kernel<<<1, 256, 0, stream>>>(bnsum, bn2g, bn2b, bnscale, bnshift, N);

    // ---- layer 3 ----
    gemm_kernel<<<gemm_grid3, 256, 0, stream>>>(hB, W3, h3b, N, 256, 64, bnscale, bnshift);
    attn_coef_kernel<1><<<2048, 256, 0, stream>>>(h3b, a3s, a3d, lsb, ldb, lsmax3, N, nb4);
    agg_kernel<1, 1><<<nb4, 256, 0, stream>>>(h3b, lsb, ldb, row_ptr, colb, b3, nullptr,
                                              fcW, ub, vb, lsmax3, N);

    // ---- edge output ----
    prep_kernel<<<1, 64, 0, stream>>>(mlpW2, mlpb2, fcW, fcb, w2f, c2);
    edge_out_kernel<<<(E + 255) / 256, 256, 0, stream>>>(ei, ea, mlpW1, mlpb1, w2f, c2,
                                                         ub, vb, out, E);
}